// Round 9
// baseline (90.343 us; speedup 1.0000x reference)
//
#include <hip/hip_runtime.h>

// CompressImageGPU: bilinear down(0.5, antialias) -> up -> +8x8 block noise -> clip,
// composed into one separable 6-tap conv on x.
// Round 8 (resubmit; prior bench was an infra failure): NO LDS, NO BARRIER.
// Each thread computes a 4x4 output patch (4 rows x 4 cols) by streaming its
// 10-row input window through 3 rotating f32x4 register buffers (depth-2
// prefetch). All weights/indices compile-time constant; row-edge cases
// (q==0 / q==127) are wave-uniform branches. NT stores, XCD-chunked swizzle.

typedef float f32x4 __attribute__((ext_vector_type(4)));

namespace {
constexpr int IMG = 512;
constexpr float I32 = 1.0f / 32.0f;
constexpr float I7  = 1.0f / 7.0f;
constexpr float I28 = 1.0f / 28.0f;
}

__device__ __forceinline__ f32x4 vfma(float w, f32x4 a, f32x4 acc) {
  acc.x = fmaf(w, a.x, acc.x); acc.y = fmaf(w, a.y, acc.y);
  acc.z = fmaf(w, a.z, acc.z); acc.w = fmaf(w, a.w, acc.w);
  return acc;
}

__global__ __launch_bounds__(512, 8) void compress_fused8_kernel(
    const float* __restrict__ x, const float* __restrict__ bn,
    float* __restrict__ out) {
  // XCD-chunked bijective swizzle (nwg = 3072, divisible by 8).
  const int nwg = gridDim.x;
  const int cpx = nwg >> 3;
  const int bid = blockIdx.x;
  const int logical = (bid & 7) * cpx + (bid >> 3);
  const int tg = logical & 31;      // quad-group 0..31 (16 rows per block)
  const int plane = logical >> 5;   // 0..95
  const int b = plane / 3;
  const int tid = threadIdx.x;
  const int cg = tid & 127;         // column group: cols 4cg..4cg+3
  const int qs = tid >> 7;          // quad slot 0..3 (uniform per wave)
  const int q  = tg * 4 + qs;       // row quad 0..127 -> rows 4q..4q+3
  const int gy0 = 4 * q;
  const int gx0 = 4 * cg;

  const float* xp = x + (size_t)plane * (IMG * IMG);
  float* op = out + (size_t)plane * (IMG * IMG);

  // rows 4q..4q+3 lie in one 8-row noise band (band = q>>1)
  const float nzv =
      (bn[(size_t)b * 4096 + (q >> 1) * 64 + (cg >> 1)] - 0.5f) * 0.02f;

  const bool left  = (cg == 0);
  const bool right = (cg == 127);
  const int A0 = left ? 0 : (right ? IMG - 12 : gx0 - 4);  // f[i] = x[A0+i]

  auto rowp = [&](int j) -> const f32x4* {
    int g = gy0 - 3 + j;
    g = max(0, min(IMG - 1, g));
    return (const f32x4*)(xp + (size_t)g * IMG + A0);
  };

  auto hconv = [&](f32x4 qa, f32x4 qb, f32x4 qc) -> f32x4 {
    const float f0 = qa.x, f1 = qa.y, f2 = qa.z, f3 = qa.w;
    const float f4_ = qb.x, f5 = qb.y, f6 = qb.z, f7 = qb.w;
    const float f8 = qc.x, f9 = qc.y, f10 = qc.z, f11 = qc.w;
    f32x4 h;
    if (left) {  // f[i] = x[i]
      h.x = (3.f * f0 + 3.f * f1 + f2) * I7;
      h.y = 9*I28*f0 + (9*I28 + I32)*f1 + (3*I28 + 3*I32)*f2 + 3*I32*f3 + I32*f4_;
      h.z = 3*I28*f0 + (3*I28 + 3*I32)*f1 + (I28 + 9*I32)*f2 + 9*I32*f3 + 3*I32*f4_;
      h.w = (3.f*f1 + 9.f*f2 + 10.f*f3 + 6.f*f4_ + 3.f*f5 + f6) * I32;
    } else if (right) {  // f[i] = x[500+i]
      h.x = (f5 + 3.f*f6 + 6.f*f7 + 10.f*f8 + 9.f*f9 + 3.f*f10) * I32;
      h.y = 3*I32*f7 + 9*I32*f8 + (I28 + 9*I32)*f9 + (3*I28 + 3*I32)*f10 + 3*I28*f11;
      h.z = I32*f7 + 3*I32*f8 + (3*I28 + 3*I32)*f9 + (9*I28 + I32)*f10 + 9*I28*f11;
      h.w = (f9 + 3.f*f10 + 3.f*f11) * I7;
    } else {  // f[i] = x[gx0-4+i]
      h.x = (f1 + 3.f*f2 + 6.f*f3 + 10.f*f4_ + 9.f*f5 + 3.f*f6) * I32;
      h.y = (3.f*f3 + 9.f*f4_ + 10.f*f5 + 6.f*f6 + 3.f*f7 + f8) * I32;
      h.z = (f3 + 3.f*f4_ + 6.f*f5 + 10.f*f6 + 9.f*f7 + 3.f*f8) * I32;
      h.w = (3.f*f5 + 9.f*f6 + 10.f*f7 + 6.f*f8 + 3.f*f9 + f10) * I32;
    }
    return h;
  };

  f32x4 acc0 = {0.f,0.f,0.f,0.f}, acc1 = acc0, acc2 = acc0, acc3 = acc0;
  const int kind = (q == 0) ? 1 : ((q == 127) ? 2 : 0);  // wave-uniform

  // v-accumulation steps: window row j holds h of global row gy0-3+j (clamped)
#define STEP(J, H)                                                             \
  if (kind == 0) {                                                             \
    if ((J) == 0) { acc0 = vfma(1*I32, H, acc0); }                             \
    if ((J) == 1) { acc0 = vfma(3*I32, H, acc0); }                             \
    if ((J) == 2) { acc0 = vfma(6*I32, H, acc0); acc1 = vfma(3*I32, H, acc1);  \
                    acc2 = vfma(1*I32, H, acc2); }                             \
    if ((J) == 3) { acc0 = vfma(10*I32, H, acc0); acc1 = vfma(9*I32, H, acc1); \
                    acc2 = vfma(3*I32, H, acc2); }                             \
    if ((J) == 4) { acc0 = vfma(9*I32, H, acc0); acc1 = vfma(10*I32, H, acc1); \
                    acc2 = vfma(6*I32, H, acc2); acc3 = vfma(3*I32, H, acc3); }\
    if ((J) == 5) { acc0 = vfma(3*I32, H, acc0); acc1 = vfma(6*I32, H, acc1);  \
                    acc2 = vfma(10*I32, H, acc2); acc3 = vfma(9*I32, H, acc3);}\
    if ((J) == 6) { acc1 = vfma(3*I32, H, acc1); acc2 = vfma(9*I32, H, acc2);  \
                    acc3 = vfma(10*I32, H, acc3); }                            \
    if ((J) == 7) { acc1 = vfma(1*I32, H, acc1); acc2 = vfma(3*I32, H, acc2);  \
                    acc3 = vfma(6*I32, H, acc3); }                             \
    if ((J) == 8) { acc3 = vfma(3*I32, H, acc3); }                             \
    if ((J) == 9) { acc3 = vfma(1*I32, H, acc3); }                             \
  } else if (kind == 1) { /* q==0: gy=0..3; j>=3 are rows 0..6 */              \
    if ((J) == 3) { acc0 = vfma(3*I7, H, acc0); acc1 = vfma(9*I28, H, acc1);   \
                    acc2 = vfma(3*I28, H, acc2); }                             \
    if ((J) == 4) { acc0 = vfma(3*I7, H, acc0);                                \
                    acc1 = vfma(9*I28 + I32, H, acc1);                         \
                    acc2 = vfma(3*I28 + 3*I32, H, acc2);                       \
                    acc3 = vfma(3*I32, H, acc3); }                             \
    if ((J) == 5) { acc0 = vfma(I7, H, acc0);                                  \
                    acc1 = vfma(3*I28 + 3*I32, H, acc1);                       \
                    acc2 = vfma(I28 + 9*I32, H, acc2);                         \
                    acc3 = vfma(9*I32, H, acc3); }                             \
    if ((J) == 6) { acc1 = vfma(3*I32, H, acc1); acc2 = vfma(9*I32, H, acc2);  \
                    acc3 = vfma(10*I32, H, acc3); }                            \
    if ((J) == 7) { acc1 = vfma(I32, H, acc1); acc2 = vfma(3*I32, H, acc2);    \
                    acc3 = vfma(6*I32, H, acc3); }                             \
    if ((J) == 8) { acc3 = vfma(3*I32, H, acc3); }                             \
    if ((J) == 9) { acc3 = vfma(I32, H, acc3); }                               \
  } else { /* q==127: gy=508..511; j = row-505, j>6 clamp dup of 511 */        \
    if ((J) == 0) { acc0 = vfma(1*I32, H, acc0); }                             \
    if ((J) == 1) { acc0 = vfma(3*I32, H, acc0); }                             \
    if ((J) == 2) { acc0 = vfma(6*I32, H, acc0); acc1 = vfma(3*I32, H, acc1);  \
                    acc2 = vfma(1*I32, H, acc2); }                             \
    if ((J) == 3) { acc0 = vfma(10*I32, H, acc0); acc1 = vfma(9*I32, H, acc1); \
                    acc2 = vfma(3*I32, H, acc2); }                             \
    if ((J) == 4) { acc0 = vfma(9*I32, H, acc0);                               \
                    acc1 = vfma(I28 + 9*I32, H, acc1);                         \
                    acc2 = vfma(3*I28 + 3*I32, H, acc2);                       \
                    acc3 = vfma(I7, H, acc3); }                                \
    if ((J) == 5) { acc0 = vfma(3*I32, H, acc0);                               \
                    acc1 = vfma(3*I28 + 3*I32, H, acc1);                       \
                    acc2 = vfma(9*I28 + I32, H, acc2);                         \
                    acc3 = vfma(3*I7, H, acc3); }                              \
    if ((J) == 6) { acc1 = vfma(3*I28, H, acc1); acc2 = vfma(9*I28, H, acc2);  \
                    acc3 = vfma(3*I7, H, acc3); }                              \
  }

#define LOADR(J, A, B, C) { const f32x4* p = rowp(J); A = p[0]; B = p[1]; C = p[2]; }

  f32x4 A0v, B0v, C0v, A1v, B1v, C1v, A2v, B2v, C2v, h;
  LOADR(0, A0v, B0v, C0v)
  LOADR(1, A1v, B1v, C1v)
  LOADR(2, A2v, B2v, C2v)
  h = hconv(A0v, B0v, C0v); STEP(0, h) LOADR(3, A0v, B0v, C0v)
  h = hconv(A1v, B1v, C1v); STEP(1, h) LOADR(4, A1v, B1v, C1v)
  h = hconv(A2v, B2v, C2v); STEP(2, h) LOADR(5, A2v, B2v, C2v)
  h = hconv(A0v, B0v, C0v); STEP(3, h) LOADR(6, A0v, B0v, C0v)
  h = hconv(A1v, B1v, C1v); STEP(4, h) LOADR(7, A1v, B1v, C1v)
  h = hconv(A2v, B2v, C2v); STEP(5, h) LOADR(8, A2v, B2v, C2v)
  h = hconv(A0v, B0v, C0v); STEP(6, h) LOADR(9, A0v, B0v, C0v)
  h = hconv(A1v, B1v, C1v); STEP(7, h)
  h = hconv(A2v, B2v, C2v); STEP(8, h)
  h = hconv(A0v, B0v, C0v); STEP(9, h)
#undef LOADR
#undef STEP

#define FINISH_STORE(o, ii)                                                    \
  {                                                                            \
    f32x4 v = o;                                                               \
    v.x = fminf(1.f, fmaxf(-1.f, v.x + nzv));                                  \
    v.y = fminf(1.f, fmaxf(-1.f, v.y + nzv));                                  \
    v.z = fminf(1.f, fmaxf(-1.f, v.z + nzv));                                  \
    v.w = fminf(1.f, fmaxf(-1.f, v.w + nzv));                                  \
    __builtin_nontemporal_store(v, (f32x4*)(op + (size_t)(gy0 + ii) * IMG + gx0)); \
  }
  FINISH_STORE(acc0, 0)
  FINISH_STORE(acc1, 1)
  FINISH_STORE(acc2, 2)
  FINISH_STORE(acc3, 3)
#undef FINISH_STORE
}

extern "C" void kernel_launch(void* const* d_in, const int* in_sizes, int n_in,
                              void* d_out, int out_size, void* d_ws, size_t ws_size,
                              hipStream_t stream) {
  const float* x  = (const float*)d_in[0];
  const float* bn = (const float*)d_in[1];
  float* out = (float*)d_out;

  const int n_planes = in_sizes[0] / (IMG * IMG);  // B*C = 96
  const int nwg = 32 * n_planes;                   // 3072 (div by 8)
  compress_fused8_kernel<<<dim3(nwg), dim3(512), 0, stream>>>(x, bn, out);
}

// Round 10
// 36.593 us; speedup vs baseline: 2.4689x; 2.4689x over previous
//
#include <hip/hip_runtime.h>

// CompressImageGPU: bilinear down(0.5, antialias) -> up -> +8x8 block noise -> clip,
// composed into one separable 6-tap conv on x.
// Round 10: exact R5 structure (TY=16 full-width tiles, 512 threads, XCD-chunked
// swizzle, 2-deep pipelined loads) with ONE change: regular cached stores instead
// of non-temporal. Working set (96MB in + 98MB out) fits the 256MB Infinity
// Cache, so cached output lines stay dirty in L3 across replays instead of
// streaming to HBM every replay.

typedef float f32x4 __attribute__((ext_vector_type(4)));

namespace {
constexpr int IMG = 512;
constexpr int TY = 16;          // output rows per block
constexpr int HROWS = TY + 6;   // 22
constexpr float I32 = 1.0f / 32.0f;
constexpr float I7  = 1.0f / 7.0f;
constexpr float I28 = 1.0f / 28.0f;
}

__device__ __forceinline__ f32x4 vfma(float w, f32x4 a, f32x4 acc) {
  acc.x = fmaf(w, a.x, acc.x); acc.y = fmaf(w, a.y, acc.y);
  acc.z = fmaf(w, a.z, acc.z); acc.w = fmaf(w, a.w, acc.w);
  return acc;
}
__device__ __forceinline__ f32x4 vmul(float w, f32x4 a) {
  f32x4 r; r.x = w * a.x; r.y = w * a.y; r.z = w * a.z; r.w = w * a.w;
  return r;
}

__global__ __launch_bounds__(512) void compress_fused10_kernel(
    const float* __restrict__ x, const float* __restrict__ bn,
    float* __restrict__ out) {
  // XCD-chunked bijective swizzle (nwg % 8 == 0).
  const int nwg = gridDim.x;
  const int cpx = nwg >> 3;
  const int bid = blockIdx.x;
  const int logical = (bid & 7) * cpx + (bid >> 3);
  const int ty = logical & 31;      // y-tile 0..31
  const int plane = logical >> 5;   // 0..95
  const int b = plane / 3;
  const int y0 = ty * TY;
  const int tid = threadIdx.x;
  const int cg = tid & 127;         // column group: cols 4cg..4cg+3
  const int ts = tid >> 7;          // row slot 0..3
  const int gx0 = 4 * cg;

  __shared__ float H[HROWS][IMG];   // 44 KB
  __shared__ float nz[128];         // 64 x-blocks x 2 y-blocks noise

  const float* xp = x + (size_t)plane * (IMG * IMG);
  float* op = out + (size_t)plane * (IMG * IMG);

  if (tid < 128) {
    const int brow = (y0 >> 3) + (tid >> 6);
    const int bcol = tid & 63;
    nz[tid] = (bn[(size_t)b * 4096 + brow * 64 + bcol] - 0.5f) * 0.02f;
  }

  const bool left  = (cg == 0);
  const bool right = (cg == 127);
  const int A0 = left ? 0 : (right ? IMG - 12 : gx0 - 4);  // f[i] = x[A0+i]

  auto rowptr = [&](int r) -> const f32x4* {
    int g = y0 - 3 + r;
    g = max(0, min(IMG - 1, g));
    return (const f32x4*)(xp + (size_t)g * IMG + A0);
  };

  // ---- h-pass: rows ts, ts+4, ..., 2-deep pipelined loads ----
  f32x4 qa, qb, qc;
  { const f32x4* p = rowptr(ts); qa = p[0]; qb = p[1]; qc = p[2]; }

#pragma unroll
  for (int k = 0; k < 6; ++k) {
    const int r = ts + 4 * k;
    const int rn = r + 4;
    f32x4 na, nb, nc;
    if (rn < HROWS) { const f32x4* p = rowptr(rn); na = p[0]; nb = p[1]; nc = p[2]; }
    if (r < HROWS) {
      const float f0 = qa.x, f1 = qa.y, f2 = qa.z, f3 = qa.w;
      const float f4_ = qb.x, f5 = qb.y, f6 = qb.z, f7 = qb.w;
      const float f8 = qc.x, f9 = qc.y, f10 = qc.z, f11 = qc.w;
      f32x4 h;
      if (left) {  // f[i] = x[i]
        h.x = (3.f * f0 + 3.f * f1 + f2) * I7;
        h.y = 9*I28*f0 + (9*I28 + I32)*f1 + (3*I28 + 3*I32)*f2 + 3*I32*f3 + I32*f4_;
        h.z = 3*I28*f0 + (3*I28 + 3*I32)*f1 + (I28 + 9*I32)*f2 + 9*I32*f3 + 3*I32*f4_;
        h.w = (3.f*f1 + 9.f*f2 + 10.f*f3 + 6.f*f4_ + 3.f*f5 + f6) * I32;
      } else if (right) {  // f[i] = x[500+i]
        h.x = (f5 + 3.f*f6 + 6.f*f7 + 10.f*f8 + 9.f*f9 + 3.f*f10) * I32;
        h.y = 3*I32*f7 + 9*I32*f8 + (I28 + 9*I32)*f9 + (3*I28 + 3*I32)*f10 + 3*I28*f11;
        h.z = I32*f7 + 3*I32*f8 + (3*I28 + 3*I32)*f9 + (9*I28 + I32)*f10 + 9*I28*f11;
        h.w = (f9 + 3.f*f10 + 3.f*f11) * I7;
      } else {  // f[i] = x[gx0-4+i]
        h.x = (f1 + 3.f*f2 + 6.f*f3 + 10.f*f4_ + 9.f*f5 + 3.f*f6) * I32;
        h.y = (3.f*f3 + 9.f*f4_ + 10.f*f5 + 6.f*f6 + 3.f*f7 + f8) * I32;
        h.z = (f3 + 3.f*f4_ + 6.f*f5 + 10.f*f6 + 9.f*f7 + 3.f*f8) * I32;
        h.w = (3.f*f5 + 9.f*f6 + 10.f*f7 + 6.f*f8 + 3.f*f9 + f10) * I32;
      }
      *(f32x4*)&H[r][gx0] = h;
    }
    if (rn < HROWS) { qa = na; qb = nb; qc = nc; }
  }
  __syncthreads();

  // ---- v-pass: 4 consecutive output rows per thread from 10-row window ----
  const int wb = 4 * ts;  // H rows wb..wb+9
  const float nzv = nz[((ts >> 1) << 6) + (cg >> 1)];
  const bool top = (y0 == 0 && ts == 0);
  const bool bot = (y0 == IMG - TY && ts == 3);
  const int gy0 = y0 + 4 * ts;

#define LDQ(j) (*(const f32x4*)&H[wb + (j)][gx0])
#define FINISH_STORE(o, ii)                                                    \
  {                                                                            \
    f32x4 v = o;                                                               \
    v.x = fminf(1.f, fmaxf(-1.f, v.x + nzv));                                  \
    v.y = fminf(1.f, fmaxf(-1.f, v.y + nzv));                                  \
    v.z = fminf(1.f, fmaxf(-1.f, v.z + nzv));                                  \
    v.w = fminf(1.f, fmaxf(-1.f, v.w + nzv));                                  \
    *(f32x4*)(op + (size_t)(gy0 + ii) * IMG + gx0) = v;                        \
  }

  const f32x4 q0 = LDQ(0), q1 = LDQ(1), q2 = LDQ(2);
  const f32x4 q3 = LDQ(3), q4 = LDQ(4), q5 = LDQ(5);

  f32x4 o0;
  if (top) {
    o0 = vfma(3*I7, q3, vfma(3*I7, q4, vmul(I7, q5)));
  } else {
    o0 = vfma(I32, q0, vfma(3*I32, q1, vfma(6*I32, q2,
         vfma(10*I32, q3, vfma(9*I32, q4, vmul(3*I32, q5))))));
  }
  FINISH_STORE(o0, 0)

  const f32x4 q6 = LDQ(6), q7 = LDQ(7);
  f32x4 o1, o2;
  if (top) {
    o1 = vfma(9*I28, q3, vfma(9*I28 + I32, q4,
         vfma(3*I28 + 3*I32, q5, vfma(3*I32, q6, vmul(I32, q7)))));
    o2 = vfma(3*I28, q3, vfma(3*I28 + 3*I32, q4,
         vfma(I28 + 9*I32, q5, vfma(9*I32, q6, vmul(3*I32, q7)))));
  } else if (bot) {
    o1 = vfma(3*I32, q2, vfma(9*I32, q3, vfma(I28 + 9*I32, q4,
         vfma(3*I28 + 3*I32, q5, vmul(3*I28, q6)))));
    o2 = vfma(I32, q2, vfma(3*I32, q3, vfma(3*I28 + 3*I32, q4,
         vfma(9*I28 + I32, q5, vmul(9*I28, q6)))));
  } else {
    o1 = vfma(3*I32, q2, vfma(9*I32, q3, vfma(10*I32, q4,
         vfma(6*I32, q5, vfma(3*I32, q6, vmul(I32, q7))))));
    o2 = vfma(I32, q2, vfma(3*I32, q3, vfma(6*I32, q4,
         vfma(10*I32, q5, vfma(9*I32, q6, vmul(3*I32, q7))))));
  }
  FINISH_STORE(o1, 1)
  FINISH_STORE(o2, 2)

  const f32x4 q8 = LDQ(8), q9 = LDQ(9);
  f32x4 o3;
  if (bot) {
    o3 = vfma(I7, q4, vfma(3*I7, q5, vmul(3*I7, q6)));
  } else {
    o3 = vfma(3*I32, q4, vfma(9*I32, q5, vfma(10*I32, q6,
         vfma(6*I32, q7, vfma(3*I32, q8, vmul(I32, q9))))));
  }
  FINISH_STORE(o3, 3)
#undef FINISH_STORE
#undef LDQ
}

extern "C" void kernel_launch(void* const* d_in, const int* in_sizes, int n_in,
                              void* d_out, int out_size, void* d_ws, size_t ws_size,
                              hipStream_t stream) {
  const float* x  = (const float*)d_in[0];
  const float* bn = (const float*)d_in[1];
  float* out = (float*)d_out;

  const int n_planes = in_sizes[0] / (IMG * IMG);  // B*C = 96
  const int nwg = (IMG / TY) * n_planes;           // 32 * 96 = 3072 (div by 8)
  compress_fused10_kernel<<<dim3(nwg), dim3(512), 0, stream>>>(x, bn, out);
}